// Round 13
// baseline (18653.795 us; speedup 1.0000x reference)
//
#include <hip/hip_runtime.h>
#include <stdint.h>

// Farthest point sampling: b=16, n=65536, npoints=2048. Full-f64 decision
// pipeline (R5: harness ref is float64 ground-truth recompute; R5-R12 absmax 0).
//
// R13 = R11 (5.51 ms anchor; R12's pipelined poll REGRESSED -> detect is
// visibility-bound, spin traffic queues against the stores) + XCD-LOCAL
// RENDEZVOUS. Agent-scope ops round-trip to the device coherence point
// (~900 cy/leg; WRITE_SIZE counted every publish). But g = bid&15 under
// round-robin dispatch puts all 16 blocks of a batch on ONE XCD (bid mod 8
// = g mod 8), sharing a coherent 4 MiB L2 (~250 cy RT). So:
//  - STARTUP GATE: each block publishes s_getreg(HW_REG_XCC_ID) via agent
//    scope; every block checks all 16 of its batch match. Only then is the
//    L2 path enabled (G16: mapping is a heuristic, correctness never
//    depends on it — mismatch falls back to the R11 agent path).
//  - Fast path: publish via inline-asm `global_store_dwordx2 ... sc0`
//    (write-through L1 into the local L2), poll via `global_load_dwordx2
//    ... sc0` (L1-bypass, L2-served). Same-XCD => single L2 => coherent.
//  - Defense: fast spin escalates to agent-scope loads after 64 rounds, so
//    even wrong sc0 semantics degrade to slow-but-correct (tags make any
//    fresh observation valid). Kernel-dispatch acquire invalidates L2 and
//    end-of-kernel release flushes it (HSA model) => no cross-launch
//    stale-tag aliasing.
// Everything else is R11 verbatim: 2-word self-tagged single-writer slots
//   w0=[bd_hi32|tag|idx] w1=[bd_lo32|tag|idx], 64-B stride;
// wave0 polls, waves 1-3 wait on a parity-duplexed LDS mailbox; winner
// coords via uniform read-only P[wi]; parity double-buffer; unique 16-bit
// tags (poison 0xAAAA unmatchable); skew <= 1 iter by the rendezvous chain.

#define NBATCH   16
#define NPTS     65536
#define NPOINTS  2048
#define KBLK     16                  // blocks per batch
#define THREADS  256
#define WPB      64                  // slots (waves) per batch
#define PPB      4096                // points per block
#define PPT      16                  // points per thread
#define SLOT_U64 8                   // 64-B stride: single writer per line
#define REGION_U64 (WPB * SLOT_U64)  // 4 KB per (parity,batch)
#define XCC_OFF_U64 (2 * NBATCH * REGION_U64)   // xcc table after slot regions
#define XCC_MAGIC 0x00C0FFEEu

#define TAGOK(w) (((unsigned)((w) >> 16) & 0xFFFFu) == tag)

__device__ __forceinline__ unsigned get_xcc_id() {
    unsigned v;
    asm volatile("s_getreg_b32 %0, hwreg(HW_REG_XCC_ID)" : "=s"(v));
    return v & 0xFFu;
}

// L1-bypassing, L2-served pair load (sc0). Two loads in flight, one wait.
__device__ __forceinline__ void load2_sc0(const unsigned long long* p,
                                          unsigned long long& a,
                                          unsigned long long& b) {
    asm volatile("global_load_dwordx2 %0, %2, off sc0\n\t"
                 "global_load_dwordx2 %1, %3, off sc0\n\t"
                 "s_waitcnt vmcnt(0)"
                 : "=&v"(a), "=&v"(b)
                 : "v"(p), "v"(p + 1)
                 : "memory");
}

// Write-through store into the local L2 (sc0).
__device__ __forceinline__ void store_sc0(unsigned long long* p,
                                          unsigned long long v) {
    asm volatile("global_store_dwordx2 %0, %1, off sc0"
                 :: "v"(p), "v"(v) : "memory");
}

__global__ __launch_bounds__(THREADS, 1)
void fps_kernel(const float* __restrict__ pts, int* __restrict__ out,
                unsigned long long* __restrict__ slots)
{
    const int bid  = blockIdx.x;
    const int g    = bid & 15;       // batch (XCD co-location swizzle)
    const int blk  = bid >> 4;       // block within batch, 0..15
    const int tid  = threadIdx.x;
    const int lane = tid & 63;
    const int wave = tid >> 6;       // 0..3
    const int widx = (blk << 2) + wave;   // slot index within batch, 0..63

    const float* __restrict__ P = pts + (size_t)g * (NPTS * 3);

    __shared__ unsigned long long s_flag[2];   // [idx<<32 | tag], per parity
    __shared__ int s_same;

    // ---- startup: XCC placement exchange (agent scope, always safe) ----
    unsigned long long* xt = slots + XCC_OFF_U64 + (size_t)g * KBLK;
    if (tid == 0) {
        __hip_atomic_store(xt + blk,
                           ((unsigned long long)get_xcc_id() << 32)
                         | (unsigned long long)XCC_MAGIC,
                           __ATOMIC_RELAXED, __HIP_MEMORY_SCOPE_AGENT);
        s_flag[0] = 0ull; s_flag[1] = 0ull;
    }
    if (wave == 0) {
        unsigned long long v = 0;
        if (lane < KBLK) {
            int gu = 0;
            do {
                v = __hip_atomic_load(xt + lane, __ATOMIC_RELAXED,
                                      __HIP_MEMORY_SCOPE_AGENT);
            } while ((unsigned)v != XCC_MAGIC && ++gu < (1 << 22));
        }
        const unsigned x0 = (unsigned)__shfl((int)(unsigned)(v >> 32), 0, 64);
        const bool eq = (lane < KBLK) ? ((unsigned)(v >> 32) == x0) : true;
        const unsigned long long bal = __ballot(eq);
        if (lane == 0) s_same = (bal == ~0ull) ? 1 : 0;
    }

    // Register-resident coords (f32; exact when widened to f64) + f64 dist.
    float  x[PPT], y[PPT], z[PPT];
    double dist[PPT];
    const int base = blk * PPB;
#pragma unroll
    for (int j = 0; j < PPT; ++j) {
        const int idx = base + j * THREADS + tid;
        x[j] = P[idx * 3 + 0];
        y[j] = P[idx * 3 + 1];
        z[j] = P[idx * 3 + 2];
        dist[j] = 1e10;              // never survives iteration 0
    }
    __syncthreads();                 // covers s_flag init + s_same
    const bool fastpath = (s_same != 0);   // block-uniform

    double qx = (double)P[0], qy = (double)P[1], qz = (double)P[2];
    if (blk == 0 && tid == 0) out[g * NPOINTS] = 0;

    for (int it = 0; it < NPOINTS - 1; ++it) {
        // ---- f64 min-dist update + thread-local argmax (first-max) ----
        double bd = -1.0;
        int    bi = 0x7FFFFFFF;
        {
#pragma clang fp contract(off)
#pragma unroll
            for (int j = 0; j < PPT; ++j) {
                const double dx = (double)x[j] - qx;
                const double dy = (double)y[j] - qy;
                const double dz = (double)z[j] - qz;
                const double d  = (dx * dx + dy * dy) + dz * dz;
                const double nd = fmin(dist[j], d);
                dist[j] = nd;
                const bool t = nd > bd;          // strict: first-max kept
                bd = t ? nd : bd;
                bi = t ? (base + j * THREADS + tid) : bi;
            }
        }

        // ---- 64-lane butterfly argmax over (bd, bi) ----
#pragma unroll
        for (int m = 1; m < 64; m <<= 1) {
            const double od = __shfl_xor(bd, m, 64);
            const int    oi = __shfl_xor(bi, m, 64);
            const bool t = (od > bd) || (od == bd && oi < bi);
            bd = t ? od : bd; bi = t ? oi : bi;
        }

        const unsigned tag = (unsigned)(it + 1);
        const int par = it & 1;
        unsigned long long* rb =
            slots + (size_t)(par * NBATCH + g) * REGION_U64;

        // ---- publish: lanes 0..1 store the 2 self-tagged words ----
        {
            const unsigned long long B =
                (unsigned long long)__double_as_longlong(bd);
            const unsigned long long TI =
                  ((unsigned long long)tag << 16)
                | (unsigned long long)((unsigned)bi & 0xFFFFu);
            const unsigned long long hi32 =
                (lane == 0) ? (B >> 32) : (B & 0xFFFFFFFFull);
            if (lane < 2) {
                unsigned long long* p = rb + widx * SLOT_U64 + lane;
                const unsigned long long w = (hi32 << 32) | TI;
                if (fastpath) store_sc0(p, w);
                else __hip_atomic_store(p, w, __ATOMIC_RELAXED,
                                        __HIP_MEMORY_SCOPE_AGENT);
            }
        }

        int wi;
        if (wave == 0) {
            // ---- poll: lane i watches slot i ----
            unsigned long long* sp = rb + lane * SLOT_U64;
            __builtin_amdgcn_s_sleep(4);   // own stores can't be visible yet
            unsigned long long l0 = 0, l1 = 0;
            bool ok = false;
            if (fastpath) {
                // phase 1: XCD-L2 rounds (sc0); escalate after 64 rounds
                int g1 = 0;
                do {
                    load2_sc0(sp, l0, l1);
                    ok = TAGOK(l0) & TAGOK(l1);
                } while (!ok && ++g1 < 64);
            }
            int g2 = 0;
            while (!ok) {
                // phase 2: agent-scope rounds (always correct)
                l0 = __hip_atomic_load(sp + 0, __ATOMIC_RELAXED,
                                       __HIP_MEMORY_SCOPE_AGENT);
                l1 = __hip_atomic_load(sp + 1, __ATOMIC_RELAXED,
                                       __HIP_MEMORY_SCOPE_AGENT);
                ok = TAGOK(l0) & TAGOK(l1);
                if (++g2 > (1 << 20)) break;   // fail loud, never hang
            }

            double cd = __longlong_as_double(
                (long long)(((l0 >> 32) << 32) | (l1 >> 32)));
            int    ci = (int)(l0 & 0xFFFFull);

            // ---- 64-lane butterfly over (cd, ci) for the batch winner ----
#pragma unroll
            for (int m = 1; m < 64; m <<= 1) {
                const double od = __shfl_xor(cd, m, 64);
                const int    oi = __shfl_xor(ci, m, 64);
                const bool t = (od > cd) || (od == cd && oi < ci);
                cd = t ? od : cd; ci = t ? oi : ci;
            }

            if (lane == 0) {
                // LDS mailbox: one atomic b64 write {idx|tag}
                __hip_atomic_store(&s_flag[par],
                                   ((unsigned long long)(unsigned)ci << 32)
                                 | (unsigned long long)tag,
                                   __ATOMIC_RELAXED,
                                   __HIP_MEMORY_SCOPE_WORKGROUP);
                if (blk == 0) out[g * NPOINTS + it + 1] = ci;
            }
            wi = ci;
        } else {
            // ---- waves 1..3: spin on the LDS mailbox (intra-CU) ----
            unsigned long long fv;
            int guard = 0;
            do {
                fv = __hip_atomic_load(&s_flag[par], __ATOMIC_RELAXED,
                                       __HIP_MEMORY_SCOPE_WORKGROUP);
            } while (((unsigned)fv != tag) && ++guard < (1 << 20));
            wi = (int)(fv >> 32);
        }

        // ---- winner coords: uniform read-only fetch, per wave in parallel
        const float* pw = P + (size_t)(unsigned)wi * 3;
        qx = (double)pw[0]; qy = (double)pw[1]; qz = (double)pw[2];
    }
}

extern "C" void kernel_launch(void* const* d_in, const int* in_sizes, int n_in,
                              void* d_out, int out_size, void* d_ws, size_t ws_size,
                              hipStream_t stream) {
    (void)in_sizes; (void)n_in; (void)out_size; (void)ws_size;
    // d_in[0] = npoints (scalar, fixed 2048 per setup), d_in[1] = t_in
    const float* t_in = (const float*)d_in[1];
    int* out = (int*)d_out;
    unsigned long long* slots = (unsigned long long*)d_ws;  // 128 KB + 2 KB

    dim3 grid(NBATCH * KBLK);
    dim3 block(THREADS);
    void* args[] = { (void*)&t_in, (void*)&out, (void*)&slots };
    hipLaunchCooperativeKernel((const void*)fps_kernel, grid, block, args, 0, stream);
}

// Round 14
// 5078.505 us; speedup vs baseline: 3.6731x; 3.6731x over previous
//
#include <hip/hip_runtime.h>
#include <stdint.h>

// Farthest point sampling: b=16, n=65536, npoints=2048. Full-f64 decision
// pipeline (R5: harness ref is float64 ground-truth recompute; R5-R13 absmax 0).
//
// R14 = R11 (5.51 ms anchor) + SINGLE-TRANSACTION POLL. History:
//  R12 (pipelined poll): regressed -> detect is visibility-bound; extra spin
//      traffic queues against the stores it waits for.
//  R13 (sc0 XCD-local rendezvous): regressed 3.4x despite perfect L2
//      absorption (WRITE_SIZE 65.6MB->200B) -> sc0 alone does NOT give
//      prompt cross-CU visibility on gfx950; agent-scope via the device
//      coherence point is the only fast transport. Escalation net worked.
// This round halves spin-load rate with zero cadence change: the slot's two
// self-tagged u64 words (one 16-B span) are polled by ONE
// global_load_dwordx4 sc0 sc1 (the device-coherent-load encoding that
// agent-scope atomic loads lower to) instead of two b64 atomic loads.
// Tearing-safe: each 8-B word is written by a single b64 store and carries
// its own tag. Defense: after 32 fast rounds the spin escalates to R11's
// proven atomic-pair loop (wrong semantics degrade to R11 speed, never
// corruption). Everything else is R11 verbatim:
//  - slots: w0=[bd_hi32|tag|idx] w1=[bd_lo32|tag|idx], 64-B stride,
//    single-writer lines; parity double-buffer; tags unique (poison 0xAAAA
//    unmatchable); skew <= 1 iteration via the rendezvous chain.
//  - wave0 polls (16 pollers/batch), waves 1-3 wait on parity-duplexed LDS
//    mailbox; winner coords via uniform read-only P[wi] fetch.

#define NBATCH   16
#define NPTS     65536
#define NPOINTS  2048
#define KBLK     16                  // blocks per batch
#define THREADS  256
#define WPB      64                  // slots (waves) per batch
#define PPB      4096                // points per block
#define PPT      16                  // points per thread
#define SLOT_U64 8                   // 64-B stride: single writer per line
#define REGION_U64 (WPB * SLOT_U64)  // 4 KB per (parity,batch)

#define TAGOK(w) (((unsigned)((w) >> 16) & 0xFFFFu) == tag)

typedef unsigned int uint4v __attribute__((ext_vector_type(4)));

// One 16-B device-coherent load covering both slot words.
__device__ __forceinline__ void load_slot16(const unsigned long long* p,
                                            unsigned long long& w0,
                                            unsigned long long& w1) {
    uint4v r;
    asm volatile("global_load_dwordx4 %0, %1, off sc0 sc1\n\t"
                 "s_waitcnt vmcnt(0)"
                 : "=v"(r) : "v"(p) : "memory");
    w0 = ((unsigned long long)r.y << 32) | r.x;
    w1 = ((unsigned long long)r.w << 32) | r.z;
}

__global__ __launch_bounds__(THREADS, 1)
void fps_kernel(const float* __restrict__ pts, int* __restrict__ out,
                unsigned long long* __restrict__ slots)
{
    const int bid  = blockIdx.x;
    const int g    = bid & 15;       // batch (XCD co-location swizzle)
    const int blk  = bid >> 4;       // block within batch, 0..15
    const int tid  = threadIdx.x;
    const int lane = tid & 63;
    const int wave = tid >> 6;       // 0..3
    const int widx = (blk << 2) + wave;   // slot index within batch, 0..63

    const float* __restrict__ P = pts + (size_t)g * (NPTS * 3);

    __shared__ unsigned long long s_flag[2];   // [idx<<32 | tag], per parity

    // Register-resident coords (f32; exact when widened to f64) + f64 dist.
    float  x[PPT], y[PPT], z[PPT];
    double dist[PPT];
    const int base = blk * PPB;
#pragma unroll
    for (int j = 0; j < PPT; ++j) {
        const int idx = base + j * THREADS + tid;
        x[j] = P[idx * 3 + 0];
        y[j] = P[idx * 3 + 1];
        z[j] = P[idx * 3 + 2];
        dist[j] = 1e10;              // never survives iteration 0
    }
    if (tid == 0) { s_flag[0] = 0ull; s_flag[1] = 0ull; }
    __syncthreads();                 // once, before the loop

    double qx = (double)P[0], qy = (double)P[1], qz = (double)P[2];
    if (blk == 0 && tid == 0) out[g * NPOINTS] = 0;

    for (int it = 0; it < NPOINTS - 1; ++it) {
        // ---- f64 min-dist update + thread-local argmax (first-max) ----
        double bd = -1.0;
        int    bi = 0x7FFFFFFF;
        {
#pragma clang fp contract(off)
#pragma unroll
            for (int j = 0; j < PPT; ++j) {
                const double dx = (double)x[j] - qx;
                const double dy = (double)y[j] - qy;
                const double dz = (double)z[j] - qz;
                const double d  = (dx * dx + dy * dy) + dz * dz;
                const double nd = fmin(dist[j], d);
                dist[j] = nd;
                const bool t = nd > bd;          // strict: first-max kept
                bd = t ? nd : bd;
                bi = t ? (base + j * THREADS + tid) : bi;
            }
        }

        // ---- 64-lane butterfly argmax over (bd, bi) ----
#pragma unroll
        for (int m = 1; m < 64; m <<= 1) {
            const double od = __shfl_xor(bd, m, 64);
            const int    oi = __shfl_xor(bi, m, 64);
            const bool t = (od > bd) || (od == bd && oi < bi);
            bd = t ? od : bd; bi = t ? oi : bi;
        }

        const unsigned tag = (unsigned)(it + 1);
        const int par = it & 1;
        unsigned long long* rb =
            slots + (size_t)(par * NBATCH + g) * REGION_U64;

        // ---- publish: lanes 0..1 store the 2 self-tagged words ----
        {
            const unsigned long long B =
                (unsigned long long)__double_as_longlong(bd);
            const unsigned long long TI =
                  ((unsigned long long)tag << 16)
                | (unsigned long long)((unsigned)bi & 0xFFFFu);
            const unsigned long long hi32 =
                (lane == 0) ? (B >> 32) : (B & 0xFFFFFFFFull);
            if (lane < 2) {
                __hip_atomic_store(rb + widx * SLOT_U64 + lane,
                                   (hi32 << 32) | TI,
                                   __ATOMIC_RELAXED, __HIP_MEMORY_SCOPE_AGENT);
            }
        }

        int wi;
        if (wave == 0) {
            // ---- poll: lane i watches slot i; ONE dwordx4 per round ----
            unsigned long long* sp = rb + lane * SLOT_U64;
            __builtin_amdgcn_s_sleep(4);   // own stores can't be visible yet
            unsigned long long l0 = 0, l1 = 0;
            bool ok = false;
            int g1 = 0;
            do {
                load_slot16(sp, l0, l1);
                ok = TAGOK(l0) & TAGOK(l1);
            } while (!ok && ++g1 < 32);
            int g2 = 0;
            while (!ok) {
                // escalation: R11's proven agent atomic-pair spin
                l0 = __hip_atomic_load(sp + 0, __ATOMIC_RELAXED,
                                       __HIP_MEMORY_SCOPE_AGENT);
                l1 = __hip_atomic_load(sp + 1, __ATOMIC_RELAXED,
                                       __HIP_MEMORY_SCOPE_AGENT);
                ok = TAGOK(l0) & TAGOK(l1);
                if (++g2 > (1 << 20)) break;   // fail loud, never hang
            }

            double cd = __longlong_as_double(
                (long long)(((l0 >> 32) << 32) | (l1 >> 32)));
            int    ci = (int)(l0 & 0xFFFFull);

            // ---- 64-lane butterfly over (cd, ci) for the batch winner ----
#pragma unroll
            for (int m = 1; m < 64; m <<= 1) {
                const double od = __shfl_xor(cd, m, 64);
                const int    oi = __shfl_xor(ci, m, 64);
                const bool t = (od > cd) || (od == cd && oi < ci);
                cd = t ? od : cd; ci = t ? oi : ci;
            }

            if (lane == 0) {
                // LDS mailbox: one atomic b64 write {idx|tag}
                __hip_atomic_store(&s_flag[par],
                                   ((unsigned long long)(unsigned)ci << 32)
                                 | (unsigned long long)tag,
                                   __ATOMIC_RELAXED,
                                   __HIP_MEMORY_SCOPE_WORKGROUP);
                if (blk == 0) out[g * NPOINTS + it + 1] = ci;
            }
            wi = ci;
        } else {
            // ---- waves 1..3: spin on the LDS mailbox (intra-CU) ----
            unsigned long long fv;
            int guard = 0;
            do {
                fv = __hip_atomic_load(&s_flag[par], __ATOMIC_RELAXED,
                                       __HIP_MEMORY_SCOPE_WORKGROUP);
            } while (((unsigned)fv != tag) && ++guard < (1 << 20));
            wi = (int)(fv >> 32);
        }

        // ---- winner coords: uniform read-only fetch, per wave in parallel
        const float* pw = P + (size_t)(unsigned)wi * 3;
        qx = (double)pw[0]; qy = (double)pw[1]; qz = (double)pw[2];
    }
}

extern "C" void kernel_launch(void* const* d_in, const int* in_sizes, int n_in,
                              void* d_out, int out_size, void* d_ws, size_t ws_size,
                              hipStream_t stream) {
    (void)in_sizes; (void)n_in; (void)out_size; (void)ws_size;
    // d_in[0] = npoints (scalar, fixed 2048 per setup), d_in[1] = t_in
    const float* t_in = (const float*)d_in[1];
    int* out = (int*)d_out;
    unsigned long long* slots = (unsigned long long*)d_ws;  // 128 KB used

    dim3 grid(NBATCH * KBLK);
    dim3 block(THREADS);
    void* args[] = { (void*)&t_in, (void*)&out, (void*)&slots };
    hipLaunchCooperativeKernel((const void*)fps_kernel, grid, block, args, 0, stream);
}

// Round 15
// 4838.511 us; speedup vs baseline: 3.8553x; 1.0496x over previous
//
#include <hip/hip_runtime.h>
#include <stdint.h>

// Farthest point sampling: b=16, n=65536, npoints=2048. Full-f64 decision
// pipeline (R5: harness ref is float64 ground-truth recompute; R5-R14 absmax 0).
//
// R15 = R14 (5.08 ms anchor) + PER-BLOCK PRE-REDUCE -> 16 publishers/slots
// per batch (was 64). Scaling laws from R10..R14: fewer participants wins,
// fewer poll transactions wins, more in-flight spin rounds loses, cache-op
// shortcuts disqualified. R9 already tried publisher-reduction but coupled
// it to __syncthreads + tid0 scalar publish (the regression); this round
// uses the cheap intra-CU path instead:
//  - waves 1..3: post (bd,bi) to LDS as TWO self-tagged b64 words
//    (workgroup-scope atomics, ds_write_b64, ~100 cy), then wait on the
//    iteration mailbox as before.
//  - wave0: spins on the 6 LDS words (tag-gated), combines 3+own candidate
//    redundantly in ALL lanes (candidates are lane-uniform -> no shuffles),
//    publishes ONE global slot (lanes 0,1, single-writer 64-B line).
//  - poll: lane i watches slot i&15 -> 16 lines/round, 4 lanes/line merge
//    in the TA; butterfly2 is 4 stages (m=1..8) instead of 6.
// Slot words: w0=[bd_hi32|tag|idx] w1=[bd_lo32|tag|idx]; dwordx4 poll with
// agent-scope escalation net (R14). Parity double-buffer, unique 16-bit
// tags (LDS words zero-init; poison 0xAAAA unmatchable), skew <= 1 iter by
// the rendezvous chain extended through the LDS hop: a block publishes
// it+2 only after its mailbox it+1, which requires detect of ALL slots
// it+1, which requires every block's publish it+1, which requires that
// block's wave0 to have consumed slots AND LDS candidates of it.

#define NBATCH   16
#define NPTS     65536
#define NPOINTS  2048
#define KBLK     16                  // blocks per batch == slots per batch
#define THREADS  256
#define PPB      4096                // points per block
#define PPT      16                  // points per thread
#define SLOT_U64 8                   // 64-B stride: single writer per line
#define REGION_U64 (KBLK * SLOT_U64) // 1 KB per (parity,batch)

#define TAGOK(w) (((unsigned)((w) >> 16) & 0xFFFFu) == tag)

typedef unsigned int uint4v __attribute__((ext_vector_type(4)));

// One 16-B device-coherent load covering both slot words.
__device__ __forceinline__ void load_slot16(const unsigned long long* p,
                                            unsigned long long& w0,
                                            unsigned long long& w1) {
    uint4v r;
    asm volatile("global_load_dwordx4 %0, %1, off sc0 sc1\n\t"
                 "s_waitcnt vmcnt(0)"
                 : "=v"(r) : "v"(p) : "memory");
    w0 = ((unsigned long long)r.y << 32) | r.x;
    w1 = ((unsigned long long)r.w << 32) | r.z;
}

__global__ __launch_bounds__(THREADS, 1)
void fps_kernel(const float* __restrict__ pts, int* __restrict__ out,
                unsigned long long* __restrict__ slots)
{
    const int bid  = blockIdx.x;
    const int g    = bid & 15;       // batch (XCD co-location swizzle)
    const int blk  = bid >> 4;       // block within batch, 0..15
    const int tid  = threadIdx.x;
    const int lane = tid & 63;
    const int wave = tid >> 6;       // 0..3

    const float* __restrict__ P = pts + (size_t)g * (NPTS * 3);

    __shared__ unsigned long long s_flag[2];        // [idx<<32|tag] / parity
    __shared__ unsigned long long s_cand[2][3][2];  // waves 1..3 candidates

    // Register-resident coords (f32; exact when widened to f64) + f64 dist.
    float  x[PPT], y[PPT], z[PPT];
    double dist[PPT];
    const int base = blk * PPB;
#pragma unroll
    for (int j = 0; j < PPT; ++j) {
        const int idx = base + j * THREADS + tid;
        x[j] = P[idx * 3 + 0];
        y[j] = P[idx * 3 + 1];
        z[j] = P[idx * 3 + 2];
        dist[j] = 1e10;              // never survives iteration 0
    }
    if (tid < 16) {                  // zero LDS protocol words (tags never 0)
        ((unsigned long long*)s_cand)[tid & 11] = 0ull;  // 12 words
        if (tid < 2) s_flag[tid] = 0ull;
    }
    __syncthreads();                 // once, before the loop

    double qx = (double)P[0], qy = (double)P[1], qz = (double)P[2];
    if (blk == 0 && tid == 0) out[g * NPOINTS] = 0;

    for (int it = 0; it < NPOINTS - 1; ++it) {
        // ---- f64 min-dist update + thread-local argmax (first-max) ----
        double bd = -1.0;
        int    bi = 0x7FFFFFFF;
        {
#pragma clang fp contract(off)
#pragma unroll
            for (int j = 0; j < PPT; ++j) {
                const double dx = (double)x[j] - qx;
                const double dy = (double)y[j] - qy;
                const double dz = (double)z[j] - qz;
                const double d  = (dx * dx + dy * dy) + dz * dz;
                const double nd = fmin(dist[j], d);
                dist[j] = nd;
                const bool t = nd > bd;          // strict: first-max kept
                bd = t ? nd : bd;
                bi = t ? (base + j * THREADS + tid) : bi;
            }
        }

        // ---- 64-lane butterfly argmax over (bd, bi) ----
#pragma unroll
        for (int m = 1; m < 64; m <<= 1) {
            const double od = __shfl_xor(bd, m, 64);
            const int    oi = __shfl_xor(bi, m, 64);
            const bool t = (od > bd) || (od == bd && oi < bi);
            bd = t ? od : bd; bi = t ? oi : bi;
        }

        const unsigned tag = (unsigned)(it + 1);
        const int par = it & 1;
        unsigned long long* rb =
            slots + (size_t)(par * NBATCH + g) * REGION_U64;

        int wi;
        if (wave != 0) {
            // ---- post candidate to LDS (2 self-tagged b64 words) ----
            if (lane == 0) {
                const unsigned long long B =
                    (unsigned long long)__double_as_longlong(bd);
                const unsigned long long TI =
                      ((unsigned long long)tag << 16)
                    | (unsigned long long)((unsigned)bi & 0xFFFFu);
                __hip_atomic_store(&s_cand[par][wave - 1][0],
                                   ((B >> 32) << 32) | TI,
                                   __ATOMIC_RELAXED,
                                   __HIP_MEMORY_SCOPE_WORKGROUP);
                __hip_atomic_store(&s_cand[par][wave - 1][1],
                                   ((B & 0xFFFFFFFFull) << 32) | TI,
                                   __ATOMIC_RELAXED,
                                   __HIP_MEMORY_SCOPE_WORKGROUP);
            }
            // ---- wait for the iteration result on the LDS mailbox ----
            unsigned long long fv;
            int guard = 0;
            do {
                fv = __hip_atomic_load(&s_flag[par], __ATOMIC_RELAXED,
                                       __HIP_MEMORY_SCOPE_WORKGROUP);
            } while (((unsigned)fv != tag) && ++guard < (1 << 20));
            wi = (int)(fv >> 32);
        } else {
            // ---- wave0: gather waves 1..3 from LDS (tag-gated spin) ----
            unsigned long long c[3][2];
            {
                int guard = 0;
                bool all;
                do {
                    all = true;
#pragma unroll
                    for (int w = 0; w < 3; ++w) {
                        c[w][0] = __hip_atomic_load(&s_cand[par][w][0],
                                      __ATOMIC_RELAXED,
                                      __HIP_MEMORY_SCOPE_WORKGROUP);
                        c[w][1] = __hip_atomic_load(&s_cand[par][w][1],
                                      __ATOMIC_RELAXED,
                                      __HIP_MEMORY_SCOPE_WORKGROUP);
                        all = all & TAGOK(c[w][0]) & TAGOK(c[w][1]);
                    }
                } while (!all && ++guard < (1 << 20));
            }
            // combine 3 + own (lane-uniform; every lane redundantly)
#pragma unroll
            for (int w = 0; w < 3; ++w) {
                const double od = __longlong_as_double((long long)(
                    ((c[w][0] >> 32) << 32) | (c[w][1] >> 32)));
                const int    oi = (int)(c[w][0] & 0xFFFFull);
                const bool t = (od > bd) || (od == bd && oi < bi);
                bd = t ? od : bd; bi = t ? oi : bi;
            }

            // ---- publish the block's slot (lanes 0..1) ----
            {
                const unsigned long long B =
                    (unsigned long long)__double_as_longlong(bd);
                const unsigned long long TI =
                      ((unsigned long long)tag << 16)
                    | (unsigned long long)((unsigned)bi & 0xFFFFu);
                const unsigned long long hi32 =
                    (lane == 0) ? (B >> 32) : (B & 0xFFFFFFFFull);
                if (lane < 2) {
                    __hip_atomic_store(rb + blk * SLOT_U64 + lane,
                                       (hi32 << 32) | TI,
                                       __ATOMIC_RELAXED,
                                       __HIP_MEMORY_SCOPE_AGENT);
                }
            }

            // ---- poll: lane i watches slot i&15; one dwordx4/round ----
            unsigned long long* sp = rb + (lane & 15) * SLOT_U64;
            __builtin_amdgcn_s_sleep(4);   // own store can't be visible yet
            unsigned long long l0 = 0, l1 = 0;
            bool ok = false;
            int g1 = 0;
            do {
                load_slot16(sp, l0, l1);
                ok = TAGOK(l0) & TAGOK(l1);
            } while (!ok && ++g1 < 32);
            int g2 = 0;
            while (!ok) {
                // escalation: proven agent atomic-pair spin
                l0 = __hip_atomic_load(sp + 0, __ATOMIC_RELAXED,
                                       __HIP_MEMORY_SCOPE_AGENT);
                l1 = __hip_atomic_load(sp + 1, __ATOMIC_RELAXED,
                                       __HIP_MEMORY_SCOPE_AGENT);
                ok = TAGOK(l0) & TAGOK(l1);
                if (++g2 > (1 << 20)) break;   // fail loud, never hang
            }

            double cd = __longlong_as_double(
                (long long)(((l0 >> 32) << 32) | (l1 >> 32)));
            int    ci = (int)(l0 & 0xFFFFull);

            // ---- 4-stage butterfly within each 16-lane group ----
#pragma unroll
            for (int m = 1; m < 16; m <<= 1) {
                const double od = __shfl_xor(cd, m, 64);
                const int    oi = __shfl_xor(ci, m, 64);
                const bool t = (od > cd) || (od == cd && oi < ci);
                cd = t ? od : cd; ci = t ? oi : ci;
            }

            if (lane == 0) {
                // LDS mailbox: one atomic b64 write {idx|tag}
                __hip_atomic_store(&s_flag[par],
                                   ((unsigned long long)(unsigned)ci << 32)
                                 | (unsigned long long)tag,
                                   __ATOMIC_RELAXED,
                                   __HIP_MEMORY_SCOPE_WORKGROUP);
                if (blk == 0) out[g * NPOINTS + it + 1] = ci;
            }
            wi = ci;
        }

        // ---- winner coords: uniform read-only fetch, per wave in parallel
        const float* pw = P + (size_t)(unsigned)wi * 3;
        qx = (double)pw[0]; qy = (double)pw[1]; qz = (double)pw[2];
    }
}

extern "C" void kernel_launch(void* const* d_in, const int* in_sizes, int n_in,
                              void* d_out, int out_size, void* d_ws, size_t ws_size,
                              hipStream_t stream) {
    (void)in_sizes; (void)n_in; (void)out_size; (void)ws_size;
    // d_in[0] = npoints (scalar, fixed 2048 per setup), d_in[1] = t_in
    const float* t_in = (const float*)d_in[1];
    int* out = (int*)d_out;
    unsigned long long* slots = (unsigned long long*)d_ws;  // 32 KB used

    dim3 grid(NBATCH * KBLK);
    dim3 block(THREADS);
    void* args[] = { (void*)&t_in, (void*)&out, (void*)&slots };
    hipLaunchCooperativeKernel((const void*)fps_kernel, grid, block, args, 0, stream);
}

// Round 16
// 4720.785 us; speedup vs baseline: 3.9514x; 1.0249x over previous
//
#include <hip/hip_runtime.h>
#include <stdint.h>

// Farthest point sampling: b=16, n=65536, npoints=2048. Full-f64 decision
// pipeline (R5: harness ref is float64 ground-truth recompute; R5-R15 absmax 0).
//
// R16 = R15 (4.84 ms; WRITE/4 signature confirmed the 16-publisher redesign)
// + two micro-cuts within the validated contention laws:
//  1. s_sleep(12) (~768 cy) before the first poll round: publish->LLC
//     visibility is ~900 cy, so R15's s_sleep(4) poll round was guaranteed
//     to fail AND its traffic queued against the in-flight publishes
//     (R12's law: spin traffic delays the stores it waits for).
//  2. Own-slot register substitution: the 4 lanes per wave whose watched
//     slot (lane&15) == blk take their candidate straight from registers
//     (tag trivially valid) and are exec-masked out of the spin load ->
//     15 lines per poll round, own store dropped from the detect condition.
// Everything else R15 verbatim: 16 blocks x 256 thr per batch; waves 1..3
// post (bd,bi) via 2 self-tagged b64 LDS words then wait on the parity
// mailbox; wave0 gathers via LDS tag-spin, combines, publishes ONE
// single-writer 64-B slot (w0=[bd_hi32|tag|idx] w1=[bd_lo32|tag|idx]),
// polls with one global_load_dwordx4 sc0 sc1 per round (escalating to the
// proven agent atomic-pair spin after 32 rounds), 4-stage butterfly,
// winner coords via uniform read-only P[wi]. Parity double-buffer, unique
// 16-bit tags (poison 0xAAAA unmatchable), skew <= 1 iteration via the
// rendezvous chain extended through the LDS hop.

#define NBATCH   16
#define NPTS     65536
#define NPOINTS  2048
#define KBLK     16                  // blocks per batch == slots per batch
#define THREADS  256
#define PPB      4096                // points per block
#define PPT      16                  // points per thread
#define SLOT_U64 8                   // 64-B stride: single writer per line
#define REGION_U64 (KBLK * SLOT_U64) // 1 KB per (parity,batch)

#define TAGOK(w) (((unsigned)((w) >> 16) & 0xFFFFu) == tag)

typedef unsigned int uint4v __attribute__((ext_vector_type(4)));

// One 16-B device-coherent load covering both slot words.
__device__ __forceinline__ void load_slot16(const unsigned long long* p,
                                            unsigned long long& w0,
                                            unsigned long long& w1) {
    uint4v r;
    asm volatile("global_load_dwordx4 %0, %1, off sc0 sc1\n\t"
                 "s_waitcnt vmcnt(0)"
                 : "=v"(r) : "v"(p) : "memory");
    w0 = ((unsigned long long)r.y << 32) | r.x;
    w1 = ((unsigned long long)r.w << 32) | r.z;
}

__global__ __launch_bounds__(THREADS, 1)
void fps_kernel(const float* __restrict__ pts, int* __restrict__ out,
                unsigned long long* __restrict__ slots)
{
    const int bid  = blockIdx.x;
    const int g    = bid & 15;       // batch (XCD co-location swizzle)
    const int blk  = bid >> 4;       // block within batch, 0..15
    const int tid  = threadIdx.x;
    const int lane = tid & 63;
    const int wave = tid >> 6;       // 0..3

    const float* __restrict__ P = pts + (size_t)g * (NPTS * 3);

    __shared__ unsigned long long s_flag[2];        // [idx<<32|tag] / parity
    __shared__ unsigned long long s_cand[2][3][2];  // waves 1..3 candidates

    // Register-resident coords (f32; exact when widened to f64) + f64 dist.
    float  x[PPT], y[PPT], z[PPT];
    double dist[PPT];
    const int base = blk * PPB;
#pragma unroll
    for (int j = 0; j < PPT; ++j) {
        const int idx = base + j * THREADS + tid;
        x[j] = P[idx * 3 + 0];
        y[j] = P[idx * 3 + 1];
        z[j] = P[idx * 3 + 2];
        dist[j] = 1e10;              // never survives iteration 0
    }
    if (tid < 16) {                  // zero LDS protocol words (tags never 0)
        ((unsigned long long*)s_cand)[tid & 11] = 0ull;  // 12 words
        if (tid < 2) s_flag[tid] = 0ull;
    }
    __syncthreads();                 // once, before the loop

    double qx = (double)P[0], qy = (double)P[1], qz = (double)P[2];
    if (blk == 0 && tid == 0) out[g * NPOINTS] = 0;

    for (int it = 0; it < NPOINTS - 1; ++it) {
        // ---- f64 min-dist update + thread-local argmax (first-max) ----
        double bd = -1.0;
        int    bi = 0x7FFFFFFF;
        {
#pragma clang fp contract(off)
#pragma unroll
            for (int j = 0; j < PPT; ++j) {
                const double dx = (double)x[j] - qx;
                const double dy = (double)y[j] - qy;
                const double dz = (double)z[j] - qz;
                const double d  = (dx * dx + dy * dy) + dz * dz;
                const double nd = fmin(dist[j], d);
                dist[j] = nd;
                const bool t = nd > bd;          // strict: first-max kept
                bd = t ? nd : bd;
                bi = t ? (base + j * THREADS + tid) : bi;
            }
        }

        // ---- 64-lane butterfly argmax over (bd, bi) ----
#pragma unroll
        for (int m = 1; m < 64; m <<= 1) {
            const double od = __shfl_xor(bd, m, 64);
            const int    oi = __shfl_xor(bi, m, 64);
            const bool t = (od > bd) || (od == bd && oi < bi);
            bd = t ? od : bd; bi = t ? oi : bi;
        }

        const unsigned tag = (unsigned)(it + 1);
        const int par = it & 1;
        unsigned long long* rb =
            slots + (size_t)(par * NBATCH + g) * REGION_U64;

        int wi;
        if (wave != 0) {
            // ---- post candidate to LDS (2 self-tagged b64 words) ----
            if (lane == 0) {
                const unsigned long long B =
                    (unsigned long long)__double_as_longlong(bd);
                const unsigned long long TI =
                      ((unsigned long long)tag << 16)
                    | (unsigned long long)((unsigned)bi & 0xFFFFu);
                __hip_atomic_store(&s_cand[par][wave - 1][0],
                                   ((B >> 32) << 32) | TI,
                                   __ATOMIC_RELAXED,
                                   __HIP_MEMORY_SCOPE_WORKGROUP);
                __hip_atomic_store(&s_cand[par][wave - 1][1],
                                   ((B & 0xFFFFFFFFull) << 32) | TI,
                                   __ATOMIC_RELAXED,
                                   __HIP_MEMORY_SCOPE_WORKGROUP);
            }
            // ---- wait for the iteration result on the LDS mailbox ----
            unsigned long long fv;
            int guard = 0;
            do {
                fv = __hip_atomic_load(&s_flag[par], __ATOMIC_RELAXED,
                                       __HIP_MEMORY_SCOPE_WORKGROUP);
            } while (((unsigned)fv != tag) && ++guard < (1 << 20));
            wi = (int)(fv >> 32);
        } else {
            // ---- wave0: gather waves 1..3 from LDS (tag-gated spin) ----
            unsigned long long c[3][2];
            {
                int guard = 0;
                bool all;
                do {
                    all = true;
#pragma unroll
                    for (int w = 0; w < 3; ++w) {
                        c[w][0] = __hip_atomic_load(&s_cand[par][w][0],
                                      __ATOMIC_RELAXED,
                                      __HIP_MEMORY_SCOPE_WORKGROUP);
                        c[w][1] = __hip_atomic_load(&s_cand[par][w][1],
                                      __ATOMIC_RELAXED,
                                      __HIP_MEMORY_SCOPE_WORKGROUP);
                        all = all & TAGOK(c[w][0]) & TAGOK(c[w][1]);
                    }
                } while (!all && ++guard < (1 << 20));
            }
            // combine 3 + own (lane-uniform; every lane redundantly)
#pragma unroll
            for (int w = 0; w < 3; ++w) {
                const double od = __longlong_as_double((long long)(
                    ((c[w][0] >> 32) << 32) | (c[w][1] >> 32)));
                const int    oi = (int)(c[w][0] & 0xFFFFull);
                const bool t = (od > bd) || (od == bd && oi < bi);
                bd = t ? od : bd; bi = t ? oi : bi;
            }

            // block candidate words (used for publish AND own-slot subst.)
            const unsigned long long B =
                (unsigned long long)__double_as_longlong(bd);
            const unsigned long long TI =
                  ((unsigned long long)tag << 16)
                | (unsigned long long)((unsigned)bi & 0xFFFFu);
            const unsigned long long own0 = ((B >> 32) << 32) | TI;
            const unsigned long long own1 = ((B & 0xFFFFFFFFull) << 32) | TI;

            // ---- publish the block's slot (lanes 0..1) ----
            if (lane < 2) {
                __hip_atomic_store(rb + blk * SLOT_U64 + lane,
                                   (lane == 0) ? own0 : own1,
                                   __ATOMIC_RELAXED,
                                   __HIP_MEMORY_SCOPE_AGENT);
            }

            // ---- poll: lane i watches slot i&15, EXCEPT its own block's
            //      slot which comes from registers (tag trivially valid).
            //      15 lines/round; sleep tuned to store-visible latency ----
            unsigned long long* sp = rb + (lane & 15) * SLOT_U64;
            const bool own = ((lane & 15) == blk);
            unsigned long long l0 = own0, l1 = own1;
            bool ok = own;
            __builtin_amdgcn_s_sleep(12);  // ~768 cy: skip guaranteed-miss rounds
            int g1 = 0;
            while (!ok && g1 < 32) {
                load_slot16(sp, l0, l1);
                ok = TAGOK(l0) & TAGOK(l1);
                ++g1;
            }
            int g2 = 0;
            while (!ok) {
                // escalation: proven agent atomic-pair spin
                l0 = __hip_atomic_load(sp + 0, __ATOMIC_RELAXED,
                                       __HIP_MEMORY_SCOPE_AGENT);
                l1 = __hip_atomic_load(sp + 1, __ATOMIC_RELAXED,
                                       __HIP_MEMORY_SCOPE_AGENT);
                ok = TAGOK(l0) & TAGOK(l1);
                if (++g2 > (1 << 20)) break;   // fail loud, never hang
            }

            double cd = __longlong_as_double(
                (long long)(((l0 >> 32) << 32) | (l1 >> 32)));
            int    ci = (int)(l0 & 0xFFFFull);

            // ---- 4-stage butterfly within each 16-lane group ----
#pragma unroll
            for (int m = 1; m < 16; m <<= 1) {
                const double od = __shfl_xor(cd, m, 64);
                const int    oi = __shfl_xor(ci, m, 64);
                const bool t = (od > cd) || (od == cd && oi < ci);
                cd = t ? od : cd; ci = t ? oi : ci;
            }

            if (lane == 0) {
                // LDS mailbox: one atomic b64 write {idx|tag}
                __hip_atomic_store(&s_flag[par],
                                   ((unsigned long long)(unsigned)ci << 32)
                                 | (unsigned long long)tag,
                                   __ATOMIC_RELAXED,
                                   __HIP_MEMORY_SCOPE_WORKGROUP);
                if (blk == 0) out[g * NPOINTS + it + 1] = ci;
            }
            wi = ci;
        }

        // ---- winner coords: uniform read-only fetch, per wave in parallel
        const float* pw = P + (size_t)(unsigned)wi * 3;
        qx = (double)pw[0]; qy = (double)pw[1]; qz = (double)pw[2];
    }
}

extern "C" void kernel_launch(void* const* d_in, const int* in_sizes, int n_in,
                              void* d_out, int out_size, void* d_ws, size_t ws_size,
                              hipStream_t stream) {
    (void)in_sizes; (void)n_in; (void)out_size; (void)ws_size;
    // d_in[0] = npoints (scalar, fixed 2048 per setup), d_in[1] = t_in
    const float* t_in = (const float*)d_in[1];
    int* out = (int*)d_out;
    unsigned long long* slots = (unsigned long long*)d_ws;  // 32 KB used

    dim3 grid(NBATCH * KBLK);
    dim3 block(THREADS);
    void* args[] = { (void*)&t_in, (void*)&out, (void*)&slots };
    hipLaunchCooperativeKernel((const void*)fps_kernel, grid, block, args, 0, stream);
}